// Round 1
// baseline (2042.643 us; speedup 1.0000x reference)
//
#include <hip/hip_runtime.h>
#include <cstdint>
#include <cstddef>

// Problem constants
#define B_    16
#define T_    32
#define H_    512
#define P_    1024        // 32*32 spatial
#define NPOS  16384       // B_*P_
#define NG    2048        // 4*H_

typedef __attribute__((ext_vector_type(8))) short short8;
typedef __attribute__((ext_vector_type(4))) float f32x4;

__device__ __forceinline__ unsigned short f2bf(float f) {
  uint32_t u = __float_as_uint(f);
  u += 0x7fffu + ((u >> 16) & 1u);     // RNE
  return (unsigned short)(u >> 16);
}
__device__ __forceinline__ float bflo(uint32_t u) { return __uint_as_float(u << 16); }
__device__ __forceinline__ float bfhi(uint32_t u) { return __uint_as_float(u & 0xffff0000u); }

__device__ __forceinline__ float sigf(float x) {
  return __builtin_amdgcn_rcpf(1.0f + __expf(-x));
}
__device__ __forceinline__ float tanhf_(float x) {
  return 1.0f - 2.0f * __builtin_amdgcn_rcpf(__expf(2.0f * x) + 1.0f);
}

__device__ __forceinline__ void gload_lds16(const void* g, void* l) {
  __builtin_amdgcn_global_load_lds(
      (const __attribute__((address_space(1))) void*)g,
      (__attribute__((address_space(3))) void*)l, 16, 0, 0);
}

// ---------------- repack kernels ----------------
// Wp[r][k] = bf16(Wc[o][1+k]),  r = ch*4+g,  o = g*512+ch  (k-contiguous rows)
__global__ void repack_w(const float* __restrict__ Wc, const float* __restrict__ bconv,
                         unsigned short* __restrict__ Wp, float* __restrict__ w0x,
                         float* __restrict__ bx) {
  int idx = blockIdx.x * 256 + threadIdx.x;       // 2048*512 exact
  int r = idx >> 9, k = idx & 511;
  int ch = r >> 2, g = r & 3;
  int o = g * 512 + ch;
  Wp[idx] = f2bf(Wc[o * 513 + 1 + k]);
  if (k == 0) { w0x[r] = Wc[o * 513]; bx[r] = bconv[o]; }
}

// wpp[j][c] = W_post[0][c][j],  j = dy*3+dx  (c-contiguous)
__global__ void repack_wpost(const float* __restrict__ Wpost, float* __restrict__ wpp) {
  int idx = blockIdx.x * 256 + threadIdx.x;
  if (idx >= 9 * 512) return;
  int j = idx >> 9, c = idx & 511;
  wpp[idx] = Wpost[c * 9 + j];
}

// ---------------- fused gates-GEMM + LSTM pointwise ----------------
// grid (16, 128): blockIdx.x -> 128 gate-rows (32 ch), blockIdx.y -> 128 positions
__global__ __launch_bounds__(256, 3)
void lstm_step(const unsigned short* __restrict__ Wp,
               const unsigned short* __restrict__ hprev,
               unsigned short* __restrict__ hnext,
               float* __restrict__ Cst,
               const float* __restrict__ w0x, const float* __restrict__ bxv,
               const float* __restrict__ xin, int t) {
  __shared__ unsigned short As[128 * 64];   // W tile   [row r][k], XOR-swizzled chunks
  __shared__ unsigned short Bs[128 * 64];   // h tile   [pos][k],   XOR-swizzled chunks

  const int tid = threadIdx.x;
  const int lane = tid & 63;
  const int wv = tid >> 6;
  const int wm = wv >> 1, wn = wv & 1;      // 2x2 waves over 128x128 tile
  const int q = lane >> 4, l = lane & 15;

  const int r0 = blockIdx.x * 128;          // gate-row base
  const int n0 = blockIdx.y * 128;          // position base

  // staging map: lds byte j*4096 + tid*16 -> row j*32 + (tid>>3), stored chunk tid&7
  const int srow = tid >> 3;
  const int lchunk = (tid & 7) ^ (srow & 7);
  const unsigned short* gA = Wp   + (size_t)(r0 + srow) * 512 + lchunk * 8;
  const unsigned short* gB = hprev + (size_t)(n0 + srow) * 512 + lchunk * 8;
  char* lA = (char*)As + wv * 1024;
  char* lB = (char*)Bs + wv * 1024;

  f32x4 acc[4][4] = {};

  for (int kc = 0; kc < 512; kc += 64) {
#pragma unroll
    for (int j = 0; j < 4; ++j)
      gload_lds16(gA + (size_t)j * (32 * 512) + kc, lA + j * 4096);
#pragma unroll
    for (int j = 0; j < 4; ++j)
      gload_lds16(gB + (size_t)j * (32 * 512) + kc, lB + j * 4096);
    __syncthreads();

#pragma unroll
    for (int kk = 0; kk < 2; ++kk) {
      short8 af[4], bf_[4];
#pragma unroll
      for (int mi = 0; mi < 4; ++mi) {
        int row = wm * 64 + mi * 16 + l;
        int sidx = row * 64 + (((kk * 4 + q) ^ (row & 7)) * 8);
        af[mi] = *(const short8*)(As + sidx);
      }
#pragma unroll
      for (int ni = 0; ni < 4; ++ni) {
        int row = wn * 64 + ni * 16 + l;
        int sidx = row * 64 + (((kk * 4 + q) ^ (row & 7)) * 8);
        bf_[ni] = *(const short8*)(Bs + sidx);
      }
#pragma unroll
      for (int mi = 0; mi < 4; ++mi)
#pragma unroll
        for (int ni = 0; ni < 4; ++ni)
          acc[mi][ni] = __builtin_amdgcn_mfma_f32_16x16x32_bf16(af[mi], bf_[ni], acc[mi][ni], 0, 0, 0);
    }
    __syncthreads();
  }

  // ---- epilogue: lane's 4 regs of acc[mi][ni] = (i,f,o,g) for one (ch,pos) ----
  float xv[4]; int posL[4]; size_t cbase[4];
#pragma unroll
  for (int ni = 0; ni < 4; ++ni) {
    posL[ni] = wn * 64 + ni * 16 + l;
    int pos = n0 + posL[ni];
    int b = pos >> 10, p = pos & 1023;
    xv[ni] = xin[((b * T_ + t) << 10) + p];
    cbase[ni] = ((size_t)b << 19) + p;    // b*512*1024 + p
  }
  const int ch0 = blockIdx.x * 32;
#pragma unroll
  for (int mi = 0; mi < 4; ++mi) {
    int chl = wm * 16 + mi * 4 + q;                    // local ch 0..31
    int rg = r0 + wm * 64 + mi * 16 + q * 4;           // global row of reg0
    float4 w0 = *(const float4*)(w0x + rg);
    float4 bb = *(const float4*)(bxv + rg);
    int ch = ch0 + chl;
#pragma unroll
    for (int ni = 0; ni < 4; ++ni) {
      f32x4 g = acc[mi][ni];
      float gi = g[0] + w0.x * xv[ni] + bb.x;
      float gf = g[1] + w0.y * xv[ni] + bb.y;
      float go = g[2] + w0.z * xv[ni] + bb.z;
      float gg = g[3] + w0.w * xv[ni] + bb.w;
      size_t cidx = cbase[ni] + ((size_t)ch << 10);
      float cold = Cst[cidx];
      float cn = sigf(gf) * cold + sigf(gi) + tanhf_(gg);
      float hn = sigf(go) + tanhf_(cn);
      Cst[cidx] = cn;
      As[posL[ni] * 32 + chl] = f2bf(hn);              // stash for coalesced store
    }
  }
  __syncthreads();
  {
    int pl = tid >> 1;
    int chh = (tid & 1) << 4;
    const uint4* src = (const uint4*)(As + pl * 32 + chh);
    unsigned short* dst = hnext + (size_t)(n0 + pl) * 512 + ch0 + chh;
    ((uint4*)dst)[0] = src[0];
    ((uint4*)dst)[1] = src[1];
  }
}

// ---------------- 3x3 post conv (512ch -> 1) ----------------
// one wave per output pixel; lane covers 8 channels
__global__ __launch_bounds__(256)
void post_conv(const unsigned short* __restrict__ h, const float* __restrict__ wpp,
               const float* __restrict__ bpost, float* __restrict__ out, int t) {
  int wid = blockIdx.x * 4 + (threadIdx.x >> 6);   // 0..16383
  int lane = threadIdx.x & 63;
  int b = wid >> 10, p = wid & 1023;
  int py = p >> 5, px = p & 31;
  int c0 = lane << 3;
  float acc = 0.f;
#pragma unroll
  for (int dy = -1; dy <= 1; ++dy) {
    int ny = py + dy;
    if ((unsigned)ny > 31u) continue;
#pragma unroll
    for (int dx = -1; dx <= 1; ++dx) {
      int nx = px + dx;
      if ((unsigned)nx > 31u) continue;
      int j = (dy + 1) * 3 + (dx + 1);
      const uint4 hv = *(const uint4*)(h + ((size_t)((b << 10) + (ny << 5) + nx) << 9) + c0);
      const float4 wa = *(const float4*)(wpp + (j << 9) + c0);
      const float4 wb = *(const float4*)(wpp + (j << 9) + c0 + 4);
      acc += bflo(hv.x) * wa.x + bfhi(hv.x) * wa.y
           + bflo(hv.y) * wa.z + bfhi(hv.y) * wa.w
           + bflo(hv.z) * wb.x + bfhi(hv.z) * wb.y
           + bflo(hv.w) * wb.z + bfhi(hv.w) * wb.w;
    }
  }
#pragma unroll
  for (int off = 1; off < 64; off <<= 1)
    acc += __shfl_xor(acc, off, 64);
  if (lane == 0)
    out[((b * T_ + t) << 10) + p] = acc + bpost[0];
}

// ---------------- launch ----------------
extern "C" void kernel_launch(void* const* d_in, const int* in_sizes, int n_in,
                              void* d_out, int out_size, void* d_ws, size_t ws_size,
                              hipStream_t stream) {
  const float* x     = (const float*)d_in[0];
  const float* Wconv = (const float*)d_in[1];
  const float* bconv = (const float*)d_in[2];
  const float* Wpost = (const float*)d_in[3];
  const float* bpost = (const float*)d_in[4];
  float* out = (float*)d_out;
  char* ws = (char*)d_ws;

  // workspace layout (bytes)
  unsigned short* h0  = (unsigned short*)(ws);                 // 16 MB
  unsigned short* h1  = (unsigned short*)(ws + 16777216);      // 16 MB
  float*          Cst = (float*)(ws + 33554432);               // 32 MB
  unsigned short* Wp  = (unsigned short*)(ws + 67108864);      // 2 MB
  float*          w0x = (float*)(ws + 69206016);               // 8 KB
  float*          bx  = (float*)(ws + 69214208);               // 8 KB
  float*          wpp = (float*)(ws + 69222400);               // 18 KB

  hipMemsetAsync(h0, 0, 16777216, stream);
  hipMemsetAsync(Cst, 0, 33554432, stream);
  repack_w<<<4096, 256, 0, stream>>>(Wconv, bconv, Wp, w0x, bx);
  repack_wpost<<<18, 256, 0, stream>>>(Wpost, wpp);

  unsigned short* hp = h0;
  unsigned short* hn = h1;
  for (int t = 0; t < T_; ++t) {
    lstm_step<<<dim3(16, 128), 256, 0, stream>>>(Wp, hp, hn, Cst, w0x, bx, x, t);
    post_conv<<<4096, 256, 0, stream>>>(hn, wpp, bpost, out, t);
    unsigned short* tmp = hp; hp = hn; hn = tmp;
  }
}

// Round 2
// 2000.730 us; speedup vs baseline: 1.0209x; 1.0209x over previous
//
#include <hip/hip_runtime.h>
#include <cstdint>
#include <cstddef>

// Problem constants
#define B_    16
#define T_    32
#define H_    512
#define P_    1024        // 32*32 spatial
#define NPOS  16384       // B_*P_
#define NG    2048        // 4*H_

typedef __attribute__((ext_vector_type(8))) short short8;
typedef __attribute__((ext_vector_type(4))) float f32x4;

__device__ __forceinline__ unsigned short f2bf(float f) {
  uint32_t u = __float_as_uint(f);
  u += 0x7fffu + ((u >> 16) & 1u);     // RNE
  return (unsigned short)(u >> 16);
}
__device__ __forceinline__ float bflo(uint32_t u) { return __uint_as_float(u << 16); }
__device__ __forceinline__ float bfhi(uint32_t u) { return __uint_as_float(u & 0xffff0000u); }

__device__ __forceinline__ float sigf(float x) {
  return __builtin_amdgcn_rcpf(1.0f + __expf(-x));
}
__device__ __forceinline__ float tanhf_(float x) {
  return 1.0f - 2.0f * __builtin_amdgcn_rcpf(__expf(2.0f * x) + 1.0f);
}

__device__ __forceinline__ void gload_lds16(const void* g, void* l) {
  __builtin_amdgcn_global_load_lds(
      (const __attribute__((address_space(1))) void*)g,
      (__attribute__((address_space(3))) void*)l, 16, 0, 0);
}

// ---------------- repack kernels ----------------
// Wp[r][k] = bf16(Wc[o][1+k]),  r = ch*4+g,  o = g*512+ch  (k-contiguous rows)
__global__ void repack_w(const float* __restrict__ Wc, const float* __restrict__ bconv,
                         unsigned short* __restrict__ Wp, float* __restrict__ w0x,
                         float* __restrict__ bx) {
  int idx = blockIdx.x * 256 + threadIdx.x;       // 2048*512 exact
  int r = idx >> 9, k = idx & 511;
  int ch = r >> 2, g = r & 3;
  int o = g * 512 + ch;
  Wp[idx] = f2bf(Wc[o * 513 + 1 + k]);
  if (k == 0) { w0x[r] = Wc[o * 513]; bx[r] = bconv[o]; }
}

// wpp[j][c] = W_post[0][c][j],  j = dy*3+dx  (c-contiguous)
__global__ void repack_wpost(const float* __restrict__ Wpost, float* __restrict__ wpp) {
  int idx = blockIdx.x * 256 + threadIdx.x;
  if (idx >= 9 * 512) return;
  int j = idx >> 9, c = idx & 511;
  wpp[idx] = Wpost[c * 9 + j];
}

// ---------------- fused gates-GEMM + LSTM pointwise ----------------
// grid (8, 128): blockIdx.x -> 256 gate-rows (64 ch), blockIdx.y -> 128 positions
__global__ __launch_bounds__(256, 2)
void lstm_step(const unsigned short* __restrict__ Wp,
               const unsigned short* __restrict__ hprev,
               unsigned short* __restrict__ hnext,
               _Float16* __restrict__ Cst,
               const float* __restrict__ w0x, const float* __restrict__ bxv,
               const float* __restrict__ xin, int t) {
  __shared__ unsigned short As[256 * 64];   // W tile   [row r][k], XOR-swizzled chunks (32 KB)
  __shared__ unsigned short Bs[128 * 64];   // h tile   [pos][k],   XOR-swizzled chunks (16 KB)

  const int tid = threadIdx.x;
  const int lane = tid & 63;
  const int wv = tid >> 6;
  const int wm = wv >> 1, wn = wv & 1;      // 2x2 waves over 256x128 tile
  const int q = lane >> 4, l = lane & 15;

  const int r0 = blockIdx.x * 256;          // gate-row base
  const int n0 = blockIdx.y * 128;          // position base

  // staging map: lds byte j*4096 + tid*16 -> row j*32 + (tid>>3), stored chunk tid&7
  const int srow = tid >> 3;
  const int lchunk = (tid & 7) ^ (srow & 7);
  const unsigned short* gA = Wp    + (size_t)(r0 + srow) * 512 + lchunk * 8;
  const unsigned short* gB = hprev + (size_t)(n0 + srow) * 512 + lchunk * 8;
  char* lA = (char*)As + wv * 1024;
  char* lB = (char*)Bs + wv * 1024;

  f32x4 acc[8][4] = {};

  for (int kc = 0; kc < 512; kc += 64) {
#pragma unroll
    for (int j = 0; j < 8; ++j)
      gload_lds16(gA + (size_t)j * (32 * 512) + kc, lA + j * 4096);
#pragma unroll
    for (int j = 0; j < 4; ++j)
      gload_lds16(gB + (size_t)j * (32 * 512) + kc, lB + j * 4096);
    __syncthreads();

#pragma unroll
    for (int kk = 0; kk < 2; ++kk) {
      short8 af[8], bf_[4];
#pragma unroll
      for (int mi = 0; mi < 8; ++mi) {
        int row = wm * 128 + mi * 16 + l;
        int sidx = row * 64 + (((kk * 4 + q) ^ (row & 7)) * 8);
        af[mi] = *(const short8*)(As + sidx);
      }
#pragma unroll
      for (int ni = 0; ni < 4; ++ni) {
        int row = wn * 64 + ni * 16 + l;
        int sidx = row * 64 + (((kk * 4 + q) ^ (row & 7)) * 8);
        bf_[ni] = *(const short8*)(Bs + sidx);
      }
#pragma unroll
      for (int mi = 0; mi < 8; ++mi)
#pragma unroll
        for (int ni = 0; ni < 4; ++ni)
          acc[mi][ni] = __builtin_amdgcn_mfma_f32_16x16x32_bf16(af[mi], bf_[ni], acc[mi][ni], 0, 0, 0);
    }
    __syncthreads();
  }

  // ---- epilogue: lane's 4 regs of acc[mi][ni] = (i,f,o,g) for one (ch,pos) ----
  float xv[4]; int posL[4]; size_t cbase[4];
#pragma unroll
  for (int ni = 0; ni < 4; ++ni) {
    posL[ni] = wn * 64 + ni * 16 + l;
    int pos = n0 + posL[ni];
    int b = pos >> 10, p = pos & 1023;
    xv[ni] = xin[((b * T_ + t) << 10) + p];
    cbase[ni] = ((size_t)b << 19) + p;    // b*512*1024 + p
  }
  const int ch0 = blockIdx.x * 64;
#pragma unroll
  for (int mi = 0; mi < 8; ++mi) {
    int chl = wm * 32 + mi * 4 + q;                    // local ch 0..63
    int rg = r0 + wm * 128 + mi * 16 + q * 4;          // global row of reg0
    float4 w0 = *(const float4*)(w0x + rg);
    float4 bb = *(const float4*)(bxv + rg);
    int ch = ch0 + chl;
#pragma unroll
    for (int ni = 0; ni < 4; ++ni) {
      f32x4 g = acc[mi][ni];
      float gi = g[0] + w0.x * xv[ni] + bb.x;
      float gf = g[1] + w0.y * xv[ni] + bb.y;
      float go = g[2] + w0.z * xv[ni] + bb.z;
      float gg = g[3] + w0.w * xv[ni] + bb.w;
      size_t cidx = cbase[ni] + ((size_t)ch << 10);
      float cold = (float)Cst[cidx];
      float cn = sigf(gf) * cold + sigf(gi) + tanhf_(gg);
      float hn = sigf(go) + tanhf_(cn);
      Cst[cidx] = (_Float16)cn;
      As[posL[ni] * 64 + chl] = f2bf(hn);              // stash for coalesced store
    }
  }
  __syncthreads();
  {
    int pl = tid >> 1;                 // 0..127 local pos
    int chh = (tid & 1) << 5;          // 0 or 32 shorts (64 B)
    const uint4* src = (const uint4*)(As + pl * 64 + chh);
    unsigned short* dst = hnext + (size_t)(n0 + pl) * 512 + ch0 + chh;
    ((uint4*)dst)[0] = src[0];
    ((uint4*)dst)[1] = src[1];
    ((uint4*)dst)[2] = src[2];
    ((uint4*)dst)[3] = src[3];
  }
}

// ---------------- 3x3 post conv (512ch -> 1) ----------------
// one wave per output pixel; lane covers 8 channels
__global__ __launch_bounds__(256)
void post_conv(const unsigned short* __restrict__ h, const float* __restrict__ wpp,
               const float* __restrict__ bpost, float* __restrict__ out, int t) {
  int wid = blockIdx.x * 4 + (threadIdx.x >> 6);   // 0..16383
  int lane = threadIdx.x & 63;
  int b = wid >> 10, p = wid & 1023;
  int py = p >> 5, px = p & 31;
  int c0 = lane << 3;
  float acc = 0.f;
#pragma unroll
  for (int dy = -1; dy <= 1; ++dy) {
    int ny = py + dy;
    if ((unsigned)ny > 31u) continue;
#pragma unroll
    for (int dx = -1; dx <= 1; ++dx) {
      int nx = px + dx;
      if ((unsigned)nx > 31u) continue;
      int j = (dy + 1) * 3 + (dx + 1);
      const uint4 hv = *(const uint4*)(h + ((size_t)((b << 10) + (ny << 5) + nx) << 9) + c0);
      const float4 wa = *(const float4*)(wpp + (j << 9) + c0);
      const float4 wb = *(const float4*)(wpp + (j << 9) + c0 + 4);
      acc += bflo(hv.x) * wa.x + bfhi(hv.x) * wa.y
           + bflo(hv.y) * wa.z + bfhi(hv.y) * wa.w
           + bflo(hv.z) * wb.x + bfhi(hv.z) * wb.y
           + bflo(hv.w) * wb.z + bfhi(hv.w) * wb.w;
    }
  }
#pragma unroll
  for (int off = 1; off < 64; off <<= 1)
    acc += __shfl_xor(acc, off, 64);
  if (lane == 0)
    out[((b * T_ + t) << 10) + p] = acc + bpost[0];
}

// ---------------- launch ----------------
extern "C" void kernel_launch(void* const* d_in, const int* in_sizes, int n_in,
                              void* d_out, int out_size, void* d_ws, size_t ws_size,
                              hipStream_t stream) {
  const float* x     = (const float*)d_in[0];
  const float* Wconv = (const float*)d_in[1];
  const float* bconv = (const float*)d_in[2];
  const float* Wpost = (const float*)d_in[3];
  const float* bpost = (const float*)d_in[4];
  float* out = (float*)d_out;
  char* ws = (char*)d_ws;

  // workspace layout (bytes)
  unsigned short* h0  = (unsigned short*)(ws);                 // 16 MB
  unsigned short* h1  = (unsigned short*)(ws + 16777216);      // 16 MB
  _Float16*       Cst = (_Float16*)(ws + 33554432);            // 16 MB (fp16 state)
  unsigned short* Wp  = (unsigned short*)(ws + 50331648);      // 2 MB
  float*          w0x = (float*)(ws + 52428800);               // 8 KB
  float*          bx  = (float*)(ws + 52436992);               // 8 KB
  float*          wpp = (float*)(ws + 52445184);               // 18 KB

  hipMemsetAsync(h0, 0, 16777216, stream);
  hipMemsetAsync(Cst, 0, 16777216, stream);
  repack_w<<<4096, 256, 0, stream>>>(Wconv, bconv, Wp, w0x, bx);
  repack_wpost<<<18, 256, 0, stream>>>(Wpost, wpp);

  unsigned short* hp = h0;
  unsigned short* hn = h1;
  for (int t = 0; t < T_; ++t) {
    lstm_step<<<dim3(8, 128), 256, 0, stream>>>(Wp, hp, hn, Cst, w0x, bx, x, t);
    post_conv<<<4096, 256, 0, stream>>>(hn, wpp, bpost, out, t);
    unsigned short* tmp = hp; hp = hn; hn = tmp;
  }
}